// Round 2
// baseline (406.548 us; speedup 1.0000x reference)
//
#include <hip/hip_runtime.h>

// Problem constants (fixed by the reference)
#define H_DIM   1024
#define G_DIM   128
#define N_DIM   384            // 3*G
#define M_TOTAL 65536          // 32*2048 rows
#define BM      64             // rows per block
// LDS x-buffer: 64 rows x 32 f16 = 4 KB, double-buffered

typedef _Float16 half8  __attribute__((ext_vector_type(8)));
typedef _Float16 half4  __attribute__((ext_vector_type(4)));
typedef __fp16   fp16x2 __attribute__((ext_vector_type(2)));
typedef float    f32x4  __attribute__((ext_vector_type(4)));

__device__ __forceinline__ float fast_sigmoid(float v) {
    return 1.0f / (1.0f + __expf(-v));
}
__device__ __forceinline__ float fast_tanh(float v) {
    return 1.0f - 2.0f / (__expf(2.0f * v) + 1.0f);
}

// 4 f32 -> 4 f16 with RTZ (same rounding as the previous cvt8 path)
__device__ __forceinline__ half4 cvt4(f32x4 v) {
    fp16x2 p0 = __builtin_amdgcn_cvt_pkrtz(v[0], v[1]);
    fp16x2 p1 = __builtin_amdgcn_cvt_pkrtz(v[2], v[3]);
    half4 h;
    h[0] = (_Float16)p0[0]; h[1] = (_Float16)p0[1];
    h[2] = (_Float16)p1[0]; h[3] = (_Float16)p1[1];
    return h;
}

// weight_ih (384x1024 fp32 row-major = B^T, K contiguous) -> f16 fragments,
// fragment-linear: frag id f = ct*32 + ktg (ktg = 32-wide K group), layout
// wf[f*512 + lane*8]: lane holds B^T[col=ct*16+(lane&15)][k=ktg*32+(lane>>4)*8 ..+8]
__global__ __launch_bounds__(256) void prep_w_kernel(const float* __restrict__ w,
                                                     _Float16* __restrict__ wf) {
    int gid  = blockIdx.x * 256 + threadIdx.x;   // 0 .. 49151
    int lane = gid & 63;
    int fid  = gid >> 6;
    int ktg  = fid & 31;
    int ct   = fid >> 5;
    int col  = ct * 16 + (lane & 15);
    int kb   = ktg * 32 + (lane >> 4) * 8;
    const f32x4* src = (const f32x4*)(w + (size_t)col * H_DIM + kb);
    f32x4 v0 = src[0], v1 = src[1];
    half8 h;
    #pragma unroll
    for (int j = 0; j < 4; ++j) { h[j] = (_Float16)v0[j]; h[4 + j] = (_Float16)v1[j]; }
    *(half8*)(wf + (size_t)gid * 8) = h;
}

// ---- raw barrier / waitcnt ----
// gfx9 simm16: vmcnt[3:0]=bits3:0, expcnt=bits6:4, lgkmcnt=bits11:8, vmcnt[5:4]=bits15:14
#define FENCE() asm volatile("" ::: "memory")
#define WAITV(N)    { FENCE(); __builtin_amdgcn_s_waitcnt(0x0F70 | (N)); FENCE(); }  // vmcnt(N) only
#define WAITLGKM0() { FENCE(); __builtin_amdgcn_s_waitcnt(0xC07F); FENCE(); }        // lgkmcnt(0) only
// barrier that does NOT drain vmcnt (register prefetches stay in flight)
#define BARRW()     { WAITLGKM0(); __builtin_amdgcn_s_barrier(); FENCE(); }

__global__ __launch_bounds__(512, 4) void ping_main_kernel(
    const float* __restrict__ x, const _Float16* __restrict__ wf,
    const float* __restrict__ bias_ih, const float* __restrict__ bias_hh,
    const float* __restrict__ lin_w, const float* __restrict__ lin_b,
    float* __restrict__ out)
{
    __shared__ _Float16 shX[2 * 2048];   // 8 KB: 2 buffers of 64 rows x 32 f16
    __shared__ float sh_out[BM];

    const int t    = threadIdx.x;       // 0..511
    const int lane = t & 63;
    const int wv   = t >> 6;            // wave 0..7
    const int ln   = lane & 15;
    const int quad = lane >> 4;

    if (t < BM) sh_out[t] = 0.0f;

    const size_t row0 = (size_t)blockIdx.x * BM;

    // --- reg-staged x path: wave wv stages rows 8wv..8wv+7 ---
    // lane l: row = 8wv + l/8, f32 cols (l&7)*4 .. +4  (one dwordx4 per step)
    const int drow = wv * 8 + (lane >> 3);                 // 0..63
    const int dcol = (lane & 7) * 4;
    const float* xsrc = x + (row0 + drow) * (size_t)H_DIM + dcol;
    // ds_write target: 8 B of f16 at [row][dcol] (row-major, 32 f16 = 64 B rows)
    _Float16* wdst = &shX[drow * 32 + dcol];               // + parity*2048 elems

    // --- A fragment read address: lane (ln,quad), rt: A[rt*16+ln][quad*8..+8]
    // f16 row-major => one ds_read_b128 per rt. Bank mapping is uniform
    // (8 accesses/bank = per-op minimum) both for reads and the b64 writes,
    // so no swizzle is needed.
    const char* aBase = (const char*)&shX[0] + ln * 64 + quad * 16;  // + rt*1024 + parity*4096

    // --- B fragment pointers: wave wv owns ct in {wv, wv+8, wv+16} so the
    // (r,z,n) triple for gate column g = 16*wv + ln stays lane-local. ---
    const _Float16* pb[3];
    #pragma unroll
    for (int i = 0; i < 3; ++i)
        pb[i] = wf + (size_t)((wv + 8 * i) * 32) * 512 + lane * 8;

    f32x4 acc[3][4];
    #pragma unroll
    for (int i = 0; i < 3; ++i)
        #pragma unroll
        for (int rt = 0; rt < 4; ++rt)
            acc[i][rt] = (f32x4){0.f, 0.f, 0.f, 0.f};

    // Register double-buffers (all indices compile-time):
    //  g[p]  : x dwordx4 for step k (p = k&1), loaded 2 steps ahead
    //  bf[p] : wf fragments for step k (p = k&1), loaded 2 steps ahead
    f32x4 g[2];
    half8 bf[2][3];

    // --- prologue: G0,G1 + b(0),b(1) in flight; write buf0; barrier ---
    g[0] = *(const f32x4*)(xsrc);
    g[1] = *(const f32x4*)(xsrc + 32);
    #pragma unroll
    for (int i = 0; i < 3; ++i) {
        bf[0][i] = *(const half8*)(pb[i]);
        bf[1][i] = *(const half8*)(pb[i] + 512);
    }
    WAITV(7);                       // retire G0 (compiler adds exact wait if reordered)
    *(half4*)(wdst) = cvt4(g[0]);
    BARRW();                        // buf0 ready everywhere

    // Step k: prefetch G(k+2)/b(k+2), MFMA on buf[k&1], then stage buf[(k+1)&1]
    // from g[(k+1)&1]. vmcnt queue at WAITV: [G(k+1), b(k+1)x3, G(k+2), b(k+2)x3]
    // -> WAITV(7) retires G(k+1) without draining any fresh prefetch. Barriers
    // wait lgkmcnt(0) only; register prefetches live across them.
#define STEP(KB, PAR, DO_PF, WAITN, DO_STAGE) { \
    if (DO_PF) g[PAR] = *(const f32x4*)(xsrc + (size_t)((KB) + 2) * 32); \
    _Pragma("unroll") \
    for (int rt = 0; rt < 4; ++rt) { \
        half8 afr = *(const half8*)(aBase + (PAR) * 4096 + rt * 1024); \
        _Pragma("unroll") \
        for (int i = 0; i < 3; ++i) \
            acc[i][rt] = __builtin_amdgcn_mfma_f32_16x16x32_f16(afr, bf[PAR][i], acc[i][rt], 0, 0, 0); \
    } \
    if (DO_PF) { \
        _Pragma("unroll") \
        for (int i = 0; i < 3; ++i) \
            bf[PAR][i] = *(const half8*)(pb[i] + (size_t)((KB) + 2) * 512); \
    } \
    if (DO_STAGE) { \
        WAITV(WAITN); \
        *(half4*)(wdst + (((PAR) ^ 1) * 2048)) = cvt4(g[(PAR) ^ 1]); \
    } \
    BARRW(); }

    for (int kb = 0; kb < 30; kb += 2) {
        STEP(kb + 0, 0, true, 7, true);
        STEP(kb + 1, 1, true, 7, true);
    }
    STEP(30, 0, false, 3, true);    // stages G31 -> buf1 (queue: [G31, b31x3])
    STEP(31, 1, false, 0, false);   // last compute step

    // --- Epilogue: gate column g = 16*wv + ln; acc[0]=r, acc[1]=z, acc[2]=n ---
    const int g_col = 16 * wv + ln;
    const float b_ir = bias_ih[g_col];
    const float b_iz = bias_ih[G_DIM + g_col];
    const float b_in = bias_ih[2 * G_DIM + g_col];
    const float b_hr = bias_hh[g_col];
    const float b_hz = bias_hh[G_DIM + g_col];
    const float b_hn = bias_hh[2 * G_DIM + g_col];
    const float lw   = lin_w[g_col];

    #pragma unroll
    for (int rt = 0; rt < 4; ++rt) {
        #pragma unroll
        for (int reg = 0; reg < 4; ++reg) {
            const float r = fast_sigmoid(acc[0][rt][reg] + b_ir + b_hr);
            const float z = fast_sigmoid(acc[1][rt][reg] + b_iz + b_hz);
            const float n = fast_tanh(acc[2][rt][reg] + b_in + r * b_hn);
            float v = lw * (1.0f - z) * n;
            // reduce over the 16 gate columns held by this quad-row group
            v += __shfl_xor(v, 1);
            v += __shfl_xor(v, 2);
            v += __shfl_xor(v, 4);
            v += __shfl_xor(v, 8);
            if (ln == 0) atomicAdd(&sh_out[rt * 16 + quad * 4 + reg], v);
        }
    }

    __syncthreads();
    if (t < BM) out[row0 + t] = sh_out[t] + lin_b[0];
}

extern "C" void kernel_launch(void* const* d_in, const int* in_sizes, int n_in,
                              void* d_out, int out_size, void* d_ws, size_t ws_size,
                              hipStream_t stream) {
    const float* x      = (const float*)d_in[0];
    const float* w_ih   = (const float*)d_in[1];
    // d_in[2] = weight_hh: unused (hidden state is always zero in the reference)
    const float* b_ih   = (const float*)d_in[3];
    const float* b_hh   = (const float*)d_in[4];
    const float* lin_w  = (const float*)d_in[5];
    const float* lin_b  = (const float*)d_in[6];
    float* out          = (float*)d_out;
    _Float16* wf        = (_Float16*)d_ws;   // 384*1024*2 = 768 KB scratch

    hipLaunchKernelGGL(prep_w_kernel, dim3((N_DIM / 16) * 32 * 64 / 256), dim3(256), 0, stream,
                       w_ih, wf);
    hipLaunchKernelGGL(ping_main_kernel, dim3(M_TOTAL / BM), dim3(512), 0, stream,
                       x, wf, b_ih, b_hh, lin_w, lin_b, out);
}

// Round 3
// 392.142 us; speedup vs baseline: 1.0367x; 1.0367x over previous
//
#include <hip/hip_runtime.h>

// Problem constants (fixed by the reference)
#define H_DIM   1024
#define G_DIM   128
#define N_DIM   384            // 3*G
#define M_TOTAL 65536          // 32*2048 rows
#define BM      64             // rows per block
// LDS x-buffer: 64 rows x 32 f16 = 4 KB, ring of 4 (16 KB)

typedef _Float16 half8  __attribute__((ext_vector_type(8)));
typedef _Float16 half4  __attribute__((ext_vector_type(4)));
typedef __fp16   fp16x2 __attribute__((ext_vector_type(2)));
typedef float    f32x4  __attribute__((ext_vector_type(4)));

__device__ __forceinline__ float fast_sigmoid(float v) {
    return 1.0f / (1.0f + __expf(-v));
}
__device__ __forceinline__ float fast_tanh(float v) {
    return 1.0f - 2.0f / (__expf(2.0f * v) + 1.0f);
}

// 4 f32 -> 4 f16 with RTZ (same rounding as previous rounds)
__device__ __forceinline__ half4 cvt4(f32x4 v) {
    fp16x2 p0 = __builtin_amdgcn_cvt_pkrtz(v[0], v[1]);
    fp16x2 p1 = __builtin_amdgcn_cvt_pkrtz(v[2], v[3]);
    half4 h;
    h[0] = (_Float16)p0[0]; h[1] = (_Float16)p0[1];
    h[2] = (_Float16)p1[0]; h[3] = (_Float16)p1[1];
    return h;
}

// weight_ih (384x1024 fp32 row-major = B^T, K contiguous) -> f16 fragments,
// fragment-linear: frag id f = ct*32 + ktg (ktg = 32-wide K group), layout
// wf[f*512 + lane*8]: lane holds B^T[col=ct*16+(lane&15)][k=ktg*32+(lane>>4)*8 ..+8]
__global__ __launch_bounds__(256) void prep_w_kernel(const float* __restrict__ w,
                                                     _Float16* __restrict__ wf) {
    int gid  = blockIdx.x * 256 + threadIdx.x;   // 0 .. 49151
    int lane = gid & 63;
    int fid  = gid >> 6;
    int ktg  = fid & 31;
    int ct   = fid >> 5;
    int col  = ct * 16 + (lane & 15);
    int kb   = ktg * 32 + (lane >> 4) * 8;
    const f32x4* src = (const f32x4*)(w + (size_t)col * H_DIM + kb);
    f32x4 v0 = src[0], v1 = src[1];
    half8 h;
    #pragma unroll
    for (int j = 0; j < 4; ++j) { h[j] = (_Float16)v0[j]; h[4 + j] = (_Float16)v1[j]; }
    *(half8*)(wf + (size_t)gid * 8) = h;
}

// ---- raw barrier: lgkmcnt(0) drain only, vmcnt prefetches stay in flight ----
// (the compiler's SIInsertWaitcnts adds exact vmcnt waits before each register
//  use of a load result; raw s_barrier does NOT force a vmcnt(0) drain)
#define FENCE() asm volatile("" ::: "memory")
#define WAITLGKM0() { FENCE(); __builtin_amdgcn_s_waitcnt(0xC07F); FENCE(); }
#define BARRW()     { WAITLGKM0(); __builtin_amdgcn_s_barrier(); FENCE(); }

__global__ __launch_bounds__(512, 4) void ping_main_kernel(
    const float* __restrict__ x, const _Float16* __restrict__ wf,
    const float* __restrict__ bias_ih, const float* __restrict__ bias_hh,
    const float* __restrict__ lin_w, const float* __restrict__ lin_b,
    float* __restrict__ out)
{
    __shared__ _Float16 shX[4 * 2048];   // 16 KB: ring of 4 buffers, 64x32 f16
    __shared__ float sh_out[BM];

    const int t    = threadIdx.x;       // 0..511
    const int lane = t & 63;
    const int wv   = t >> 6;            // wave 0..7
    const int ln   = lane & 15;
    const int quad = lane >> 4;

    if (t < BM) sh_out[t] = 0.0f;

    const size_t row0 = (size_t)blockIdx.x * BM;

    // --- reg-staged x path: wave wv stages rows 8wv..8wv+7 ---
    // lane l: row = 8wv + l/8, f32 cols (l&7)*4 .. +4  (one dwordx4 per step)
    const int drow = wv * 8 + (lane >> 3);                 // 0..63
    const int dcol = (lane & 7) * 4;
    const float* xsrc = x + (row0 + drow) * (size_t)H_DIM + dcol;
    // ds_write target: 8 B of f16 at [row][dcol] (row-major, 32 f16 = 64 B rows)
    _Float16* wdst = &shX[drow * 32 + dcol];               // + ring*2048 elems

    // --- A fragment read address: lane (ln,quad), rt: A[rt*16+ln][quad*8..+8]
    const char* aBase = (const char*)&shX[0] + ln * 64 + quad * 16;  // + rt*1024 + ring*4096

    // --- B fragment pointers: wave wv owns ct in {wv, wv+8, wv+16} so the
    // (r,z,n) triple for gate column g = 16*wv + ln stays lane-local. ---
    const _Float16* pb[3];
    #pragma unroll
    for (int i = 0; i < 3; ++i)
        pb[i] = wf + (size_t)((wv + 8 * i) * 32) * 512 + lane * 8;

    f32x4 acc[3][4];
    #pragma unroll
    for (int i = 0; i < 3; ++i)
        #pragma unroll
        for (int rt = 0; rt < 4; ++rt)
            acc[i][rt] = (f32x4){0.f, 0.f, 0.f, 0.f};

    // Pipeline (all ring indices compile-time):
    //   g[s&3]  : x dwordx4 for step s, ISSUED at step s-5, STAGED at s-2
    //   LDS buf[s&3] : written (ds_write) at step s-2, read (MFMA) at step s
    //   bf[s&1] : wf fragments for step s, loaded at step s-2 (L2-resident)
    // Barriers only after ODD steps: write@k -> read@k+2 always has a barrier
    // in between, and read@k -> rewrite@k+2 likewise (16 barriers, not 32).
    f32x4 g[4];
    half8 bf[2][3];

    // --- prologue ---
    g[0] = *(const f32x4*)(xsrc);                       // G0
    g[1] = *(const f32x4*)(xsrc + 32);                  // G1
    g[2] = *(const f32x4*)(xsrc + 64);                  // G2
    g[3] = *(const f32x4*)(xsrc + 96);                  // G3
    #pragma unroll
    for (int i = 0; i < 3; ++i) {
        bf[0][i] = *(const half8*)(pb[i]);              // b(0)
        bf[1][i] = *(const half8*)(pb[i] + 512);        // b(1)
    }
    *(half4*)(wdst)        = cvt4(g[0]);                // stage buf0
    *(half4*)(wdst + 2048) = cvt4(g[1]);                // stage buf1
    g[0] = *(const f32x4*)(xsrc + 128);                 // G4 (slot 0 now free)
    BARRW();                                            // buf0/buf1 visible

    // Step K: MFMA on buf[K&3] x bf[K&1]; issue G(K+5); load b(K+2);
    //         stage g[(K+2)&3] -> buf[(K+2)&3]; barrier after odd K.
#define STEP(K, DO_G, DO_B, DO_S, DO_BAR) { \
    _Pragma("unroll") \
    for (int rt = 0; rt < 4; ++rt) { \
        half8 afr = *(const half8*)(aBase + ((K) & 3) * 4096 + rt * 1024); \
        _Pragma("unroll") \
        for (int i = 0; i < 3; ++i) \
            acc[i][rt] = __builtin_amdgcn_mfma_f32_16x16x32_f16(afr, bf[(K) & 1][i], acc[i][rt], 0, 0, 0); \
    } \
    if (DO_G) g[((K) + 1) & 3] = *(const f32x4*)(xsrc + (size_t)((K) + 5) * 32); \
    if (DO_B) { \
        _Pragma("unroll") \
        for (int i = 0; i < 3; ++i) \
            bf[(K) & 1][i] = *(const half8*)(pb[i] + (size_t)((K) + 2) * 512); \
    } \
    if (DO_S) *(half4*)(wdst + (((K) + 2) & 3) * 2048) = cvt4(g[((K) + 2) & 3]); \
    if (DO_BAR) BARRW(); }

    // K = 0..23: full pipeline (G(K+5) <= G28 valid)
    for (int kb = 0; kb < 24; kb += 4) {
        STEP(kb + 0, true, true, true, false);
        STEP(kb + 1, true, true, true, true);
        STEP(kb + 2, true, true, true, false);
        STEP(kb + 3, true, true, true, true);
    }
    // tail: G issue while K<=26, b/stage while K<=29
    STEP(24, true,  true,  true,  false);
    STEP(25, true,  true,  true,  true);
    STEP(26, true,  true,  true,  false);   // issues G31 (last)
    STEP(27, false, true,  true,  true);
    STEP(28, false, true,  true,  false);   // stages buf for step 30
    STEP(29, false, true,  true,  true);    // stages buf for step 31
    STEP(30, false, false, false, false);
    STEP(31, false, false, false, false);

    // --- Epilogue: gate column g = 16*wv + ln; acc[0]=r, acc[1]=z, acc[2]=n ---
    const int g_col = 16 * wv + ln;
    const float b_ir = bias_ih[g_col];
    const float b_iz = bias_ih[G_DIM + g_col];
    const float b_in = bias_ih[2 * G_DIM + g_col];
    const float b_hr = bias_hh[g_col];
    const float b_hz = bias_hh[G_DIM + g_col];
    const float b_hn = bias_hh[2 * G_DIM + g_col];
    const float lw   = lin_w[g_col];

    #pragma unroll
    for (int rt = 0; rt < 4; ++rt) {
        #pragma unroll
        for (int reg = 0; reg < 4; ++reg) {
            const float r = fast_sigmoid(acc[0][rt][reg] + b_ir + b_hr);
            const float z = fast_sigmoid(acc[1][rt][reg] + b_iz + b_hz);
            const float n = fast_tanh(acc[2][rt][reg] + b_in + r * b_hn);
            float v = lw * (1.0f - z) * n;
            // reduce over the 16 gate columns held by this quad-row group
            v += __shfl_xor(v, 1);
            v += __shfl_xor(v, 2);
            v += __shfl_xor(v, 4);
            v += __shfl_xor(v, 8);
            if (ln == 0) atomicAdd(&sh_out[rt * 16 + quad * 4 + reg], v);
        }
    }

    __syncthreads();
    if (t < BM) out[row0 + t] = sh_out[t] + lin_b[0];
}

extern "C" void kernel_launch(void* const* d_in, const int* in_sizes, int n_in,
                              void* d_out, int out_size, void* d_ws, size_t ws_size,
                              hipStream_t stream) {
    const float* x      = (const float*)d_in[0];
    const float* w_ih   = (const float*)d_in[1];
    // d_in[2] = weight_hh: unused (hidden state is always zero in the reference)
    const float* b_ih   = (const float*)d_in[3];
    const float* b_hh   = (const float*)d_in[4];
    const float* lin_w  = (const float*)d_in[5];
    const float* lin_b  = (const float*)d_in[6];
    float* out          = (float*)d_out;
    _Float16* wf        = (_Float16*)d_ws;   // 384*1024*2 = 768 KB scratch

    hipLaunchKernelGGL(prep_w_kernel, dim3((N_DIM / 16) * 32 * 64 / 256), dim3(256), 0, stream,
                       w_ih, wf);
    hipLaunchKernelGGL(ping_main_kernel, dim3(M_TOTAL / BM), dim3(512), 0, stream,
                       x, wf, b_ih, b_hh, lin_w, lin_b, out);
}